// Round 2
// baseline (810.208 us; speedup 1.0000x reference)
//
#include <hip/hip_runtime.h>

typedef _Float16 half8 __attribute__((ext_vector_type(8)));
typedef _Float16 half4v __attribute__((ext_vector_type(4)));
typedef float f32x4 __attribute__((ext_vector_type(4)));

#define BM 128
#define BK 64
#define LDK (BK + 8)   // 72 halfs = 144 B row stride: 16B-aligned b128 reads, 2-way bank alias (free)

// ---------------- W1 transpose + fp16 convert: W1[512][128] f32 -> W1T[128][512] f16 ----------
__global__ void prep_w1t(const float* __restrict__ W1, _Float16* __restrict__ W1T) {
    int idx = blockIdx.x * 256 + threadIdx.x;   // 65536 total
    int n = idx >> 9;          // 0..127
    int k = idx & 511;         // 0..511
    W1T[idx] = (_Float16)W1[k * 128 + n];
}

// ---------------- zero d_out (131072 f32x4) + denom (256 f32x4) ------------------------------
__global__ void zero_kernel(float* __restrict__ out, float* __restrict__ denom) {
    int id = blockIdx.x * 256 + threadIdx.x;    // 513 blocks -> 131328 ids, exact
    f32x4 z = {0.f, 0.f, 0.f, 0.f};
    if (id < 131072)           ((f32x4*)out)[id] = z;
    else                       ((f32x4*)denom)[id - 131072] = z;
}

// ---------------- fused: scores -> exp -> segment-pool via atomics ---------------------------
// Math: weight_i = e^{s_i - gmax} / (sum_j e^{s_j - gmax} + 1e-8)
//     => out[b]  = sum e^{s_i} x_i / (sum e^{s_j} + 1e-8 e^{gmax}).
// s is bounded (|s| <= ||W2||_1 + |b2| ~ 9) so unshifted exp is safe in f32, and the epsilon
// term is O(1e-9) relative vs denom ~ 1e2 -- below tolerance. So NO global sync needed.
__global__ __launch_bounds__(256) void fused_kernel(
        const float* __restrict__ x, const _Float16* __restrict__ W1T,
        const float* __restrict__ b1, const float* __restrict__ W2,
        const float* __restrict__ b2, const int* __restrict__ batch,
        float* __restrict__ outacc, float* __restrict__ denom) {
    __shared__ _Float16 As[BM][LDK];
    __shared__ _Float16 Bs[128][LDK];
    __shared__ float se[BM];     // exp(score) per row
    __shared__ int   sb[BM];     // segment id per row
    const int tid = threadIdx.x;
    const int wave = tid >> 6, lane = tid & 63;
    const int quad = lane >> 4, col = lane & 15;
    const long row0 = (long)blockIdx.x * BM;

    if (tid < BM) sb[tid] = batch[row0 + tid];

    f32x4 acc[2][8] = {};

    // ---- phase 1: h = x @ W1 (f16 MFMA), tile GEMM identical to prior score_kernel ----
    for (int kc = 0; kc < 512; kc += BK) {
        #pragma unroll
        for (int it = 0; it < 8; ++it) {
            int idx = it * 256 + tid;
            int r = idx >> 4, c4 = idx & 15;
            float4 v = *(const float4*)&x[(row0 + r) * 512 + kc + c4 * 4];
            half4v h; h[0] = (_Float16)v.x; h[1] = (_Float16)v.y;
                      h[2] = (_Float16)v.z; h[3] = (_Float16)v.w;
            *(half4v*)&As[r][c4 * 4] = h;
        }
        #pragma unroll
        for (int it = 0; it < 4; ++it) {
            int idx = it * 256 + tid;
            int n = idx >> 3, c8 = idx & 7;
            *(half8*)&Bs[n][c8 * 8] = *(const half8*)&W1T[n * 512 + kc + c8 * 8];
        }
        __syncthreads();
        #pragma unroll
        for (int ks = 0; ks < BK; ks += 32) {
            half8 a[2], bf[8];
            #pragma unroll
            for (int mt = 0; mt < 2; ++mt)
                a[mt] = *(half8*)&As[wave * 32 + mt * 16 + col][ks + quad * 8];
            #pragma unroll
            for (int nt = 0; nt < 8; ++nt)
                bf[nt] = *(half8*)&Bs[nt * 16 + col][ks + quad * 8];
            #pragma unroll
            for (int mt = 0; mt < 2; ++mt)
                #pragma unroll
                for (int nt = 0; nt < 8; ++nt)
                    acc[mt][nt] = __builtin_amdgcn_mfma_f32_16x16x32_f16(
                        a[mt], bf[nt], acc[mt][nt], 0, 0, 0);
        }
        __syncthreads();
    }

    // ---- epilogue: s[m] = sum_n tanh(h+b1)*W2 + b2 ; se[m] = exp(s[m]) ----
    float b1v[8], w2v[8];
    #pragma unroll
    for (int nt = 0; nt < 8; ++nt) {
        b1v[nt] = b1[nt * 16 + col];
        w2v[nt] = W2[nt * 16 + col];
    }
    float bias2 = b2[0];
    #pragma unroll
    for (int mt = 0; mt < 2; ++mt) {
        #pragma unroll
        for (int r = 0; r < 4; ++r) {
            float p = 0.f;
            #pragma unroll
            for (int nt = 0; nt < 8; ++nt)
                p += tanhf(acc[mt][nt][r] + b1v[nt]) * w2v[nt];
            #pragma unroll
            for (int off = 1; off < 16; off <<= 1) p += __shfl_xor(p, off);
            if (col == 0)
                se[wave * 32 + mt * 16 + quad * 4 + r] = __expf(p + bias2);
        }
    }
    __syncthreads();

    // ---- phase 2: pool. x re-read hits L2 (tile was just fetched). 2 row-teams x 128 lanes.
    const int team = tid >> 7, tl = tid & 127;
    const int c = tl * 4;
    f32x4 pacc = {0.f, 0.f, 0.f, 0.f};
    float esum = 0.f;
    int curseg = sb[team];
    for (int r = team; r < BM; r += 2) {
        int s = sb[r];
        if (s != curseg) {              // uniform branch within team (sb same for all lanes)
            atomicAdd(&outacc[(long)curseg * 512 + c + 0], pacc[0]);
            atomicAdd(&outacc[(long)curseg * 512 + c + 1], pacc[1]);
            atomicAdd(&outacc[(long)curseg * 512 + c + 2], pacc[2]);
            atomicAdd(&outacc[(long)curseg * 512 + c + 3], pacc[3]);
            if (tl == 0) atomicAdd(&denom[curseg], esum);
            pacc = (f32x4){0.f, 0.f, 0.f, 0.f}; esum = 0.f; curseg = s;
        }
        float e = se[r];
        f32x4 xv = *(const f32x4*)&x[(row0 + r) * 512 + c];
        pacc += e * xv;
        esum += e;
    }
    atomicAdd(&outacc[(long)curseg * 512 + c + 0], pacc[0]);
    atomicAdd(&outacc[(long)curseg * 512 + c + 1], pacc[1]);
    atomicAdd(&outacc[(long)curseg * 512 + c + 2], pacc[2]);
    atomicAdd(&outacc[(long)curseg * 512 + c + 3], pacc[3]);
    if (tl == 0) atomicAdd(&denom[curseg], esum);
}

// ---------------- out[b] /= (denom[b] + 1e-8) ------------------------------------------------
__global__ void finalize(float* __restrict__ out, const float* __restrict__ denom) {
    const int b = blockIdx.x;
    const int c = threadIdx.x * 4;
    const float dinv = 1.f / (denom[b] + 1e-8f);
    f32x4 v = *(f32x4*)&out[(long)b * 512 + c];
    v *= dinv;
    *(f32x4*)&out[(long)b * 512 + c] = v;
}

extern "C" void kernel_launch(void* const* d_in, const int* in_sizes, int n_in,
                              void* d_out, int out_size, void* d_ws, size_t ws_size,
                              hipStream_t stream) {
    const float* x     = (const float*)d_in[0];
    const int*   batch = (const int*)d_in[1];
    const float* W1    = (const float*)d_in[2];
    const float* b1    = (const float*)d_in[3];
    const float* W2    = (const float*)d_in[4];
    const float* b2    = (const float*)d_in[5];
    float* out = (float*)d_out;

    const int N = in_sizes[1];          // 262144

    // workspace layout (16B-aligned)
    _Float16* W1T = (_Float16*)d_ws;                       // 128*512*2 = 131072 B
    float*    denom = (float*)((char*)d_ws + 131072);      // 1024 floats

    prep_w1t<<<256, 256, 0, stream>>>(W1, W1T);
    zero_kernel<<<513, 256, 0, stream>>>(out, denom);
    fused_kernel<<<N / BM, 256, 0, stream>>>(x, W1T, b1, W2, b2, batch, out, denom);
    finalize<<<1024, 128, 0, stream>>>(out, denom);
}